// Round 3
// baseline (512.561 us; speedup 1.0000x reference)
//
#include <hip/hip_runtime.h>

#define BB 16
#define NN 1000
#define DD 256
#define LL 3
#define MAXNZ 256
#define MROWS (BB * NN)
#define UNR 12

// ---------------------------------------------------------------------------
// Kernel 1: build sparse structure of A = prot_contacts + eye (layer-invariant)
// ---------------------------------------------------------------------------
__global__ __launch_bounds__(256) void build_sparse(
    const float* __restrict__ contacts,
    int* __restrict__ idx, int* __restrict__ cnt, float* __restrict__ adiag)
{
    int wave = (int)((blockIdx.x * blockDim.x + threadIdx.x) >> 6);
    int lane = threadIdx.x & 63;
    if (wave >= MROWS) return;
    int b = wave / NN;
    int i = wave - b * NN;
    const float* row = contacts + (size_t)b * NN * NN + (size_t)i * NN;
    int* out = idx + (size_t)wave * MAXNZ;
    int count = 0;
    for (int j0 = 0; j0 < NN; j0 += 64) {
        int j = j0 + lane;
        float v = (j < NN) ? row[j] : 0.0f;
        bool p = (v != 0.0f) && (j != i);
        unsigned long long bal = __ballot(p);
        if (p) {
            int pre = __popcll(bal & ((1ull << lane) - 1ull));
            out[count + pre] = j;
        }
        count += __popcll(bal);
    }
    if (lane == 0) {
        cnt[wave] = count;
        adiag[wave] = row[i] + 1.0f;
    }
}

// ---------------------------------------------------------------------------
// Kernel 2: sparse attention aggregate.
// Masked-uniform unroll-12 (no serial tail), XCD-local row assignment.
// ---------------------------------------------------------------------------
__global__ __launch_bounds__(256, 4) void sparse_agg(
    const float* __restrict__ y, const float* __restrict__ x0,
    const int* __restrict__ idx, const int* __restrict__ cnt,
    const float* __restrict__ adiag, float* __restrict__ xout)
{
    // XCD-aware swizzle: 4000 blocks, 8 XCDs round-robin by bid%8.
    // XCD x processes rows [x*2000, (x+1)*2000) = batches {2x, 2x+1}:
    // per-XCD gather working set 2MB < 4MB L2.
    int bid = blockIdx.x;
    int xcd = bid & 7;
    int chunk = bid >> 3;                    // 0..499
    int row = xcd * 2000 + chunk * 4 + (int)(threadIdx.x >> 6);
    row = __builtin_amdgcn_readfirstlane(row);
    int lane = threadIdx.x & 63;
    int b = row / NN;

    const float4 y4  = *(const float4*)(y  + (size_t)row * DD + lane * 4);
    const float4 xi4 = *(const float4*)(x0 + (size_t)row * DD + lane * 4);
    const float* xb = x0 + (size_t)b * NN * DD;

    // diagonal: (exp(s_ii) + 1e-5) * (pc_ii + 1)
    float p = y4.x * xi4.x + y4.y * xi4.y + y4.z * xi4.z + y4.w * xi4.w;
    #pragma unroll
    for (int m = 32; m; m >>= 1) p += __shfl_xor(p, m);
    float wd = (__expf(p) + 1e-5f) * adiag[row];
    float denom = wd;
    float4 acc = make_float4(wd * xi4.x, wd * xi4.y, wd * xi4.z, wd * xi4.w);

    const int c = cnt[row];
    const int* ip = idx + (size_t)row * MAXNZ;
    const int iters = (c + UNR - 1) / UNR;

    for (int t = 0; t < iters; ++t) {
        int k = t * UNR;
        int4 ja = *(const int4*)(ip + k);
        int4 jb = *(const int4*)(ip + k + 4);
        int4 jc = *(const int4*)(ip + k + 8);
        int jj[UNR] = {ja.x, ja.y, ja.z, ja.w, jb.x, jb.y, jb.z, jb.w,
                       jc.x, jc.y, jc.z, jc.w};
        bool va[UNR];
        #pragma unroll
        for (int u = 0; u < UNR; ++u) {
            va[u] = (k + u) < c;
            jj[u] = va[u] ? jj[u] : 0;      // clamp: masked slots hold poison
        }
        float4 xv[UNR];
        #pragma unroll
        for (int u = 0; u < UNR; ++u)
            xv[u] = *(const float4*)(xb + (size_t)jj[u] * DD + lane * 4);
        float q[UNR];
        #pragma unroll
        for (int u = 0; u < UNR; ++u)
            q[u] = y4.x * xv[u].x + y4.y * xv[u].y + y4.z * xv[u].z + y4.w * xv[u].w;
        #pragma unroll
        for (int m = 32; m; m >>= 1) {
            #pragma unroll
            for (int u = 0; u < UNR; ++u) q[u] += __shfl_xor(q[u], m);
        }
        #pragma unroll
        for (int u = 0; u < UNR; ++u) {
            float w = __expf(va[u] ? q[u] : -1e30f);   // masked -> exp -> 0.0
            denom += w;
            acc.x += w * xv[u].x; acc.y += w * xv[u].y;
            acc.z += w * xv[u].z; acc.w += w * xv[u].w;
        }
    }
    float inv = 1.0f / denom;
    *(float4*)(xout + (size_t)row * DD + lane * 4) =
        make_float4(acc.x * inv, acc.y * inv, acc.z * inv, acc.w * inv);
}

// ---------------------------------------------------------------------------
// Kernel 3: fused GEMM  C[M,256] = op(A[M,256] @ W[256,256] + bias [+ skip])
// 128x64 tile, BK=32, 8x4 per thread -> per-k 3 ds_read_b128 vs 32 FMA.
// ---------------------------------------------------------------------------
__global__ __launch_bounds__(256) void gemm_fused(
    const float* __restrict__ A, const float* __restrict__ W,
    const float* __restrict__ bias, const float* __restrict__ skip,
    float* __restrict__ C, int relu)
{
    __shared__ float As[32][132];   // [k][m], padded
    __shared__ float Ws[32][68];    // [k][n], padded
    int tid = threadIdx.x;
    int tx = tid & 15, ty = tid >> 4;
    int mBase = blockIdx.y * 128;
    int nBase = blockIdx.x * 64;

    float acc[8][4] = {};

    int ar = tid >> 1;            // 0..127: A row within tile
    int ac = (tid & 1) * 4;       // k offset 0/4 (+8c)
    int wk = tid >> 3;            // 0..31: W k-row
    int wn = (tid & 7) * 8;       // n offset 0..56
    const float* Ag = A + (size_t)(mBase + ar) * 256 + ac;
    const float* Wg = W + (size_t)wk * 256 + nBase + wn;

    for (int kb = 0; kb < 256; kb += 32) {
        float4 a0 = *(const float4*)(Ag + kb);
        float4 a1 = *(const float4*)(Ag + kb + 8);
        float4 a2 = *(const float4*)(Ag + kb + 16);
        float4 a3 = *(const float4*)(Ag + kb + 24);
        float4 w0 = *(const float4*)(Wg + (size_t)kb * 256);
        float4 w1 = *(const float4*)(Wg + (size_t)kb * 256 + 4);
        __syncthreads();
        As[ac + 0][ar] = a0.x;  As[ac + 1][ar] = a0.y;
        As[ac + 2][ar] = a0.z;  As[ac + 3][ar] = a0.w;
        As[ac + 8][ar] = a1.x;  As[ac + 9][ar] = a1.y;
        As[ac + 10][ar] = a1.z; As[ac + 11][ar] = a1.w;
        As[ac + 16][ar] = a2.x; As[ac + 17][ar] = a2.y;
        As[ac + 18][ar] = a2.z; As[ac + 19][ar] = a2.w;
        As[ac + 24][ar] = a3.x; As[ac + 25][ar] = a3.y;
        As[ac + 26][ar] = a3.z; As[ac + 27][ar] = a3.w;
        *(float4*)&Ws[wk][wn] = w0;
        *(float4*)&Ws[wk][wn + 4] = w1;
        __syncthreads();
        #pragma unroll
        for (int k = 0; k < 32; ++k) {
            float4 w4 = *(const float4*)&Ws[k][tx * 4];
            float4 a4 = *(const float4*)&As[k][ty * 8];
            float4 a4b = *(const float4*)&As[k][ty * 8 + 4];
            float am_[8] = {a4.x, a4.y, a4.z, a4.w, a4b.x, a4b.y, a4b.z, a4b.w};
            float wn_[4] = {w4.x, w4.y, w4.z, w4.w};
            #pragma unroll
            for (int i2 = 0; i2 < 8; ++i2)
                #pragma unroll
                for (int j2 = 0; j2 < 4; ++j2)
                    acc[i2][j2] = fmaf(am_[i2], wn_[j2], acc[i2][j2]);
        }
    }

    float4 bv = make_float4(0.f, 0.f, 0.f, 0.f);
    if (bias) bv = *(const float4*)(bias + nBase + tx * 4);
    #pragma unroll
    for (int i2 = 0; i2 < 8; ++i2) {
        int m = mBase + ty * 8 + i2;
        float4 o = make_float4(acc[i2][0] + bv.x, acc[i2][1] + bv.y,
                               acc[i2][2] + bv.z, acc[i2][3] + bv.w);
        if (relu) {
            o.x = fmaxf(o.x, 0.f); o.y = fmaxf(o.y, 0.f);
            o.z = fmaxf(o.z, 0.f); o.w = fmaxf(o.w, 0.f);
        }
        if (skip) {
            float4 s4 = *(const float4*)(skip + (size_t)m * 256 + nBase + tx * 4);
            o.x += s4.x; o.y += s4.y; o.z += s4.z; o.w += s4.w;
        }
        *(float4*)(C + (size_t)m * 256 + nBase + tx * 4) = o;
    }
}

// ---------------------------------------------------------------------------
extern "C" void kernel_launch(void* const* d_in, const int* in_sizes, int n_in,
                              void* d_out, int out_size, void* d_ws, size_t ws_size,
                              hipStream_t stream)
{
    const float* x_in     = (const float*)d_in[0];
    const float* contacts = (const float*)d_in[1];
    const float* W_list   = (const float*)d_in[2];
    const float* dense_W  = (const float*)d_in[3];
    const float* dense_b  = (const float*)d_in[4];
    const float* final_W  = (const float*)d_in[5];
    const float* final_b  = (const float*)d_in[6];
    float* out = (float*)d_out;

    char* ws = (char*)d_ws;
    const size_t bufBytes = (size_t)MROWS * DD * sizeof(float);
    float* bufA = (float*)(ws);
    float* bufB = (float*)(ws + bufBytes);
    float* bufC = (float*)(ws + 2 * bufBytes);
    int*   idx  = (int*)(ws + 3 * bufBytes);
    int*   cnt  = (int*)(ws + 3 * bufBytes + (size_t)MROWS * MAXNZ * sizeof(int));
    float* adiag = (float*)((char*)cnt + (size_t)MROWS * sizeof(int));

    build_sparse<<<MROWS / 4, 256, 0, stream>>>(contacts, idx, cnt, adiag);

    dim3 ggrid(DD / 64, MROWS / 128);   // (4, 125)
    const float* curx = x_in;
    for (int l = 0; l < LL; ++l) {
        float* yv = bufA;
        float* ov = (l == 1) ? bufC : bufB;
        gemm_fused<<<ggrid, 256, 0, stream>>>(curx, W_list + (size_t)l * 65536,
                                              nullptr, nullptr, yv, 0);
        sparse_agg<<<MROWS / 4, 256, 0, stream>>>(yv, curx, idx, cnt, adiag, ov);
        gemm_fused<<<ggrid, 256, 0, stream>>>(ov, dense_W + (size_t)(l * 2 + 0) * 65536,
                                              dense_b + (size_t)(l * 2 + 0) * 256,
                                              nullptr, yv, 1);
        gemm_fused<<<ggrid, 256, 0, stream>>>(yv, dense_W + (size_t)(l * 2 + 1) * 65536,
                                              dense_b + (size_t)(l * 2 + 1) * 256,
                                              curx, ov, 1);
        curx = ov;
    }
    gemm_fused<<<ggrid, 256, 0, stream>>>(curx, final_W, final_b, nullptr, out, 0);
}

// Round 4
// 441.879 us; speedup vs baseline: 1.1600x; 1.1600x over previous
//
#include <hip/hip_runtime.h>

#define BB 16
#define NN 1000
#define DD 256
#define LL 3
#define MAXNZ 256
#define MROWS (BB * NN)

__device__ __forceinline__ float dot4(float4 a, float4 b) {
    return fmaf(a.x, b.x, fmaf(a.y, b.y, fmaf(a.z, b.z, a.w * b.w)));
}
__device__ __forceinline__ void fma4(float4& a, float w, float4 v) {
    a.x = fmaf(w, v.x, a.x); a.y = fmaf(w, v.y, a.y);
    a.z = fmaf(w, v.z, a.z); a.w = fmaf(w, v.w, a.w);
}

// ---------------------------------------------------------------------------
// Kernel 1: build sparse structure of A = prot_contacts + eye (layer-invariant)
// ---------------------------------------------------------------------------
__global__ __launch_bounds__(256) void build_sparse(
    const float* __restrict__ contacts,
    int* __restrict__ idx, int* __restrict__ cnt, float* __restrict__ adiag)
{
    int wave = (int)((blockIdx.x * blockDim.x + threadIdx.x) >> 6);
    int lane = threadIdx.x & 63;
    if (wave >= MROWS) return;
    int b = wave / NN;
    int i = wave - b * NN;
    const float* row = contacts + (size_t)b * NN * NN + (size_t)i * NN;
    int* out = idx + (size_t)wave * MAXNZ;
    int count = 0;
    for (int j0 = 0; j0 < NN; j0 += 64) {
        int j = j0 + lane;
        float v = (j < NN) ? row[j] : 0.0f;
        bool p = (v != 0.0f) && (j != i);
        unsigned long long bal = __ballot(p);
        if (p) {
            int pre = __popcll(bal & ((1ull << lane) - 1ull));
            out[count + pre] = j;
        }
        count += __popcll(bal);
    }
    if (lane == 0) {
        cnt[wave] = count;
        adiag[wave] = row[i] + 1.0f;
    }
}

// ---------------------------------------------------------------------------
// Kernel 2: sparse attention aggregate, v3.
// 16-lane group holds a full 256-dim row (lane s: dims u*64+s*4, u=0..3).
// Wave = 4 groups = 4 neighbors in flight; 2-deep index + 1-deep data pipeline.
// Reduction: 4 shfl levels per 4 neighbors; cross-group sum once per row.
// XCD-local row assignment (keeps per-XCD gather set at 2MB < 4MB L2).
// ---------------------------------------------------------------------------
__global__ __launch_bounds__(256) void sparse_agg(
    const float* __restrict__ y, const float* __restrict__ x0,
    const int* __restrict__ idx, const int* __restrict__ cnt,
    const float* __restrict__ adiag, float* __restrict__ xout)
{
    int bid = blockIdx.x;
    int xcd = bid & 7;
    int chunk = bid >> 3;
    int row = xcd * 2000 + chunk * 4 + (int)(threadIdx.x >> 6);
    row = __builtin_amdgcn_readfirstlane(row);
    int lane = threadIdx.x & 63;
    int g = lane >> 4, s = lane & 15;
    int b = row / NN;

    const float* yp = y + (size_t)row * DD + s * 4;
    float4 y0 = *(const float4*)(yp +   0);
    float4 y1 = *(const float4*)(yp +  64);
    float4 y2 = *(const float4*)(yp + 128);
    float4 y3 = *(const float4*)(yp + 192);
    const float* xip = x0 + (size_t)row * DD + s * 4;
    float4 xi0 = *(const float4*)(xip +   0);
    float4 xi1 = *(const float4*)(xip +  64);
    float4 xi2 = *(const float4*)(xip + 128);
    float4 xi3 = *(const float4*)(xip + 192);
    const float* xb = x0 + (size_t)b * NN * DD;

    // diagonal: (exp(s_ii)+1e-5) * (pc_ii+1); only group 0 contributes
    float p = dot4(y0, xi0) + dot4(y1, xi1) + dot4(y2, xi2) + dot4(y3, xi3);
    p += __shfl_xor(p, 1); p += __shfl_xor(p, 2);
    p += __shfl_xor(p, 4); p += __shfl_xor(p, 8);
    float wd = (g == 0) ? (__expf(p) + 1e-5f) * adiag[row] : 0.0f;
    float denom = wd;
    float4 a0 = make_float4(0.f, 0.f, 0.f, 0.f), a1 = a0, a2 = a0, a3 = a0;
    fma4(a0, wd, xi0); fma4(a1, wd, xi1); fma4(a2, wd, xi2); fma4(a3, wd, xi3);

    const int c = cnt[row];
    const int* ip = idx + (size_t)row * MAXNZ;
    const int iters = (c + 3) >> 2;

    // pipeline prologue: j for t=0 and t=1, data for t=0
    int j0 = (g < c) ? ip[g] : 0;
    int j1 = (4 + g < c) ? ip[4 + g] : 0;
    bool vok = g < c;
    const float* xjp = xb + (size_t)j0 * DD + s * 4;
    float4 v0 = *(const float4*)(xjp +   0);
    float4 v1 = *(const float4*)(xjp +  64);
    float4 v2 = *(const float4*)(xjp + 128);
    float4 v3 = *(const float4*)(xjp + 192);

    for (int t = 0; t < iters; ++t) {
        // prefetch index t+2 and data t+1
        int k2 = (t + 2) * 4 + g;
        int j2 = (k2 < c) ? ip[k2] : 0;
        const float* np = xb + (size_t)j1 * DD + s * 4;
        float4 n0 = *(const float4*)(np +   0);
        float4 n1 = *(const float4*)(np +  64);
        float4 n2 = *(const float4*)(np + 128);
        float4 n3 = *(const float4*)(np + 192);

        float q = dot4(y0, v0) + dot4(y1, v1) + dot4(y2, v2) + dot4(y3, v3);
        q += __shfl_xor(q, 1); q += __shfl_xor(q, 2);
        q += __shfl_xor(q, 4); q += __shfl_xor(q, 8);
        float w = vok ? __expf(q) : 0.0f;
        denom += w;
        fma4(a0, w, v0); fma4(a1, w, v1); fma4(a2, w, v2); fma4(a3, w, v3);

        v0 = n0; v1 = n1; v2 = n2; v3 = n3;
        j1 = j2;
        vok = (t + 1) * 4 + g < c;
    }

    // cross-group reduction (masks 16,32) of denom + 16 acc components
#define XG(x) x += __shfl_xor(x, 16); x += __shfl_xor(x, 32);
    XG(denom);
    XG(a0.x) XG(a0.y) XG(a0.z) XG(a0.w)
    XG(a1.x) XG(a1.y) XG(a1.z) XG(a1.w)
    XG(a2.x) XG(a2.y) XG(a2.z) XG(a2.w)
    XG(a3.x) XG(a3.y) XG(a3.z) XG(a3.w)
#undef XG

    float inv = 1.0f / denom;
    float4 o = (g == 0) ? a0 : (g == 1) ? a1 : (g == 2) ? a2 : a3;
    o.x *= inv; o.y *= inv; o.z *= inv; o.w *= inv;
    *(float4*)(xout + (size_t)row * DD + g * 64 + s * 4) = o;
}

// ---------------------------------------------------------------------------
// Kernel 3: fused GEMM  C[M,256] = op(A[M,256] @ W[256,256] + bias [+ skip])
// 128x64 tile, BK=32, 8x4 per thread.
// ---------------------------------------------------------------------------
__global__ __launch_bounds__(256) void gemm_fused(
    const float* __restrict__ A, const float* __restrict__ W,
    const float* __restrict__ bias, const float* __restrict__ skip,
    float* __restrict__ C, int relu)
{
    __shared__ float As[32][132];   // [k][m], padded
    __shared__ float Ws[32][68];    // [k][n], padded
    int tid = threadIdx.x;
    int tx = tid & 15, ty = tid >> 4;
    int mBase = blockIdx.y * 128;
    int nBase = blockIdx.x * 64;

    float acc[8][4] = {};

    int ar = tid >> 1;            // 0..127: A row within tile
    int ac = (tid & 1) * 4;       // k offset 0/4 (+8c)
    int wk = tid >> 3;            // 0..31: W k-row
    int wn = (tid & 7) * 8;       // n offset 0..56
    const float* Ag = A + (size_t)(mBase + ar) * 256 + ac;
    const float* Wg = W + (size_t)wk * 256 + nBase + wn;

    for (int kb = 0; kb < 256; kb += 32) {
        float4 a0 = *(const float4*)(Ag + kb);
        float4 a1 = *(const float4*)(Ag + kb + 8);
        float4 a2 = *(const float4*)(Ag + kb + 16);
        float4 a3 = *(const float4*)(Ag + kb + 24);
        float4 w0 = *(const float4*)(Wg + (size_t)kb * 256);
        float4 w1 = *(const float4*)(Wg + (size_t)kb * 256 + 4);
        __syncthreads();
        As[ac + 0][ar] = a0.x;  As[ac + 1][ar] = a0.y;
        As[ac + 2][ar] = a0.z;  As[ac + 3][ar] = a0.w;
        As[ac + 8][ar] = a1.x;  As[ac + 9][ar] = a1.y;
        As[ac + 10][ar] = a1.z; As[ac + 11][ar] = a1.w;
        As[ac + 16][ar] = a2.x; As[ac + 17][ar] = a2.y;
        As[ac + 18][ar] = a2.z; As[ac + 19][ar] = a2.w;
        As[ac + 24][ar] = a3.x; As[ac + 25][ar] = a3.y;
        As[ac + 26][ar] = a3.z; As[ac + 27][ar] = a3.w;
        *(float4*)&Ws[wk][wn] = w0;
        *(float4*)&Ws[wk][wn + 4] = w1;
        __syncthreads();
        #pragma unroll
        for (int k = 0; k < 32; ++k) {
            float4 w4 = *(const float4*)&Ws[k][tx * 4];
            float4 a4 = *(const float4*)&As[k][ty * 8];
            float4 a4b = *(const float4*)&As[k][ty * 8 + 4];
            float am_[8] = {a4.x, a4.y, a4.z, a4.w, a4b.x, a4b.y, a4b.z, a4b.w};
            float wn_[4] = {w4.x, w4.y, w4.z, w4.w};
            #pragma unroll
            for (int i2 = 0; i2 < 8; ++i2)
                #pragma unroll
                for (int j2 = 0; j2 < 4; ++j2)
                    acc[i2][j2] = fmaf(am_[i2], wn_[j2], acc[i2][j2]);
        }
    }

    float4 bv = make_float4(0.f, 0.f, 0.f, 0.f);
    if (bias) bv = *(const float4*)(bias + nBase + tx * 4);
    #pragma unroll
    for (int i2 = 0; i2 < 8; ++i2) {
        int m = mBase + ty * 8 + i2;
        float4 o = make_float4(acc[i2][0] + bv.x, acc[i2][1] + bv.y,
                               acc[i2][2] + bv.z, acc[i2][3] + bv.w);
        if (relu) {
            o.x = fmaxf(o.x, 0.f); o.y = fmaxf(o.y, 0.f);
            o.z = fmaxf(o.z, 0.f); o.w = fmaxf(o.w, 0.f);
        }
        if (skip) {
            float4 s4 = *(const float4*)(skip + (size_t)m * 256 + nBase + tx * 4);
            o.x += s4.x; o.y += s4.y; o.z += s4.z; o.w += s4.w;
        }
        *(float4*)(C + (size_t)m * 256 + nBase + tx * 4) = o;
    }
}

// ---------------------------------------------------------------------------
extern "C" void kernel_launch(void* const* d_in, const int* in_sizes, int n_in,
                              void* d_out, int out_size, void* d_ws, size_t ws_size,
                              hipStream_t stream)
{
    const float* x_in     = (const float*)d_in[0];
    const float* contacts = (const float*)d_in[1];
    const float* W_list   = (const float*)d_in[2];
    const float* dense_W  = (const float*)d_in[3];
    const float* dense_b  = (const float*)d_in[4];
    const float* final_W  = (const float*)d_in[5];
    const float* final_b  = (const float*)d_in[6];
    float* out = (float*)d_out;

    char* ws = (char*)d_ws;
    const size_t bufBytes = (size_t)MROWS * DD * sizeof(float);
    float* bufA = (float*)(ws);
    float* bufB = (float*)(ws + bufBytes);
    float* bufC = (float*)(ws + 2 * bufBytes);
    int*   idx  = (int*)(ws + 3 * bufBytes);
    int*   cnt  = (int*)(ws + 3 * bufBytes + (size_t)MROWS * MAXNZ * sizeof(int));
    float* adiag = (float*)((char*)cnt + (size_t)MROWS * sizeof(int));

    build_sparse<<<MROWS / 4, 256, 0, stream>>>(contacts, idx, cnt, adiag);

    dim3 ggrid(DD / 64, MROWS / 128);   // (4, 125)
    const float* curx = x_in;
    for (int l = 0; l < LL; ++l) {
        float* yv = bufA;
        float* ov = (l == 1) ? bufC : bufB;
        gemm_fused<<<ggrid, 256, 0, stream>>>(curx, W_list + (size_t)l * 65536,
                                              nullptr, nullptr, yv, 0);
        sparse_agg<<<MROWS / 4, 256, 0, stream>>>(yv, curx, idx, cnt, adiag, ov);
        gemm_fused<<<ggrid, 256, 0, stream>>>(ov, dense_W + (size_t)(l * 2 + 0) * 65536,
                                              dense_b + (size_t)(l * 2 + 0) * 256,
                                              nullptr, yv, 1);
        gemm_fused<<<ggrid, 256, 0, stream>>>(yv, dense_W + (size_t)(l * 2 + 1) * 65536,
                                              dense_b + (size_t)(l * 2 + 1) * 256,
                                              curx, ov, 1);
        curx = ov;
    }
    gemm_fused<<<ggrid, 256, 0, stream>>>(curx, final_W, final_b, nullptr, out, 0);
}

// Round 5
// 297.420 us; speedup vs baseline: 1.7234x; 1.4857x over previous
//
#include <hip/hip_runtime.h>

#define BB 16
#define NN 1000
#define DD 256
#define LL 3
#define MAXNZ 256
#define MROWS (BB * NN)

typedef _Float16 f16x8 __attribute__((ext_vector_type(8)));
typedef float f32x4 __attribute__((ext_vector_type(4)));

union H8 { _Float16 h[8]; int4 v; };

__device__ __forceinline__ float dot4(float4 a, float4 b) {
    return fmaf(a.x, b.x, fmaf(a.y, b.y, fmaf(a.z, b.z, a.w * b.w)));
}
__device__ __forceinline__ void fma4(float4& a, float w, float4 v) {
    a.x = fmaf(w, v.x, a.x); a.y = fmaf(w, v.y, a.y);
    a.z = fmaf(w, v.z, a.z); a.w = fmaf(w, v.w, a.w);
}

// ---------------------------------------------------------------------------
// Kernel 0: split+transpose all 10 weight matrices into fp16 hi/lo planes.
// wt[mat][n][k];  x = hi + lo * 2^-11  (lo stored pre-scaled by 2^11)
// ---------------------------------------------------------------------------
__global__ __launch_bounds__(256) void convert_w(
    const float* __restrict__ W_list, const float* __restrict__ dense_W,
    const float* __restrict__ final_W,
    _Float16* __restrict__ wt_hi, _Float16* __restrict__ wt_lo)
{
    __shared__ float T[64][68];
    int blk = blockIdx.x;          // 10 mats * 16 tiles
    int mat = blk >> 4;
    int tile = blk & 15;
    int tk = (tile >> 2) * 64, tn = (tile & 3) * 64;
    const float* src = (mat < 3) ? (W_list + (size_t)mat * 65536)
                     : (mat < 9) ? (dense_W + (size_t)(mat - 3) * 65536)
                                 : final_W;
    int t = threadIdx.x;
    {
        int k = t >> 2, nc = (t & 3) * 16;
        const float* sp = src + (size_t)(tk + k) * 256 + tn + nc;
        float4 v0 = *(const float4*)(sp + 0);
        float4 v1 = *(const float4*)(sp + 4);
        float4 v2 = *(const float4*)(sp + 8);
        float4 v3 = *(const float4*)(sp + 12);
        *(float4*)&T[k][nc + 0]  = v0;
        *(float4*)&T[k][nc + 4]  = v1;
        *(float4*)&T[k][nc + 8]  = v2;
        *(float4*)&T[k][nc + 12] = v3;
    }
    __syncthreads();
    int n = t >> 2, kc = (t & 3) * 16;
    H8 hh0, hh1, ll0, ll1;
    #pragma unroll
    for (int i = 0; i < 16; ++i) {
        float x = T[kc + i][n];
        _Float16 hi = (_Float16)x;
        float r = x - (float)hi;
        _Float16 lo = (_Float16)(r * 2048.0f);
        if (i < 8) { hh0.h[i] = hi; ll0.h[i] = lo; }
        else       { hh1.h[i - 8] = hi; ll1.h[i - 8] = lo; }
    }
    size_t o = (size_t)mat * 65536 + (size_t)(tn + n) * 256 + tk + kc;
    *(int4*)(wt_hi + o)     = hh0.v;
    *(int4*)(wt_hi + o + 8) = hh1.v;
    *(int4*)(wt_lo + o)     = ll0.v;
    *(int4*)(wt_lo + o + 8) = ll1.v;
}

// ---------------------------------------------------------------------------
// Kernel 1: build sparse structure of A = prot_contacts + eye (layer-invariant)
// ---------------------------------------------------------------------------
__global__ __launch_bounds__(256) void build_sparse(
    const float* __restrict__ contacts,
    int* __restrict__ idx, int* __restrict__ cnt, float* __restrict__ adiag)
{
    int wave = (int)((blockIdx.x * blockDim.x + threadIdx.x) >> 6);
    int lane = threadIdx.x & 63;
    if (wave >= MROWS) return;
    int b = wave / NN;
    int i = wave - b * NN;
    const float* row = contacts + (size_t)b * NN * NN + (size_t)i * NN;
    int* out = idx + (size_t)wave * MAXNZ;
    int count = 0;
    for (int j0 = 0; j0 < NN; j0 += 64) {
        int j = j0 + lane;
        float v = (j < NN) ? row[j] : 0.0f;
        bool p = (v != 0.0f) && (j != i);
        unsigned long long bal = __ballot(p);
        if (p) {
            int pre = __popcll(bal & ((1ull << lane) - 1ull));
            out[count + pre] = j;
        }
        count += __popcll(bal);
    }
    if (lane == 0) {
        cnt[wave] = count;
        adiag[wave] = row[i] + 1.0f;
    }
}

// ---------------------------------------------------------------------------
// Kernel 2: sparse attention aggregate (round-4 v3, unchanged).
// ---------------------------------------------------------------------------
__global__ __launch_bounds__(256) void sparse_agg(
    const float* __restrict__ y, const float* __restrict__ x0,
    const int* __restrict__ idx, const int* __restrict__ cnt,
    const float* __restrict__ adiag, float* __restrict__ xout)
{
    int bid = blockIdx.x;
    int xcd = bid & 7;
    int chunk = bid >> 3;
    int row = xcd * 2000 + chunk * 4 + (int)(threadIdx.x >> 6);
    row = __builtin_amdgcn_readfirstlane(row);
    int lane = threadIdx.x & 63;
    int g = lane >> 4, s = lane & 15;
    int b = row / NN;

    const float* yp = y + (size_t)row * DD + s * 4;
    float4 y0 = *(const float4*)(yp +   0);
    float4 y1 = *(const float4*)(yp +  64);
    float4 y2 = *(const float4*)(yp + 128);
    float4 y3 = *(const float4*)(yp + 192);
    const float* xip = x0 + (size_t)row * DD + s * 4;
    float4 xi0 = *(const float4*)(xip +   0);
    float4 xi1 = *(const float4*)(xip +  64);
    float4 xi2 = *(const float4*)(xip + 128);
    float4 xi3 = *(const float4*)(xip + 192);
    const float* xb = x0 + (size_t)b * NN * DD;

    float p = dot4(y0, xi0) + dot4(y1, xi1) + dot4(y2, xi2) + dot4(y3, xi3);
    p += __shfl_xor(p, 1); p += __shfl_xor(p, 2);
    p += __shfl_xor(p, 4); p += __shfl_xor(p, 8);
    float wd = (g == 0) ? (__expf(p) + 1e-5f) * adiag[row] : 0.0f;
    float denom = wd;
    float4 a0 = make_float4(0.f, 0.f, 0.f, 0.f), a1 = a0, a2 = a0, a3 = a0;
    fma4(a0, wd, xi0); fma4(a1, wd, xi1); fma4(a2, wd, xi2); fma4(a3, wd, xi3);

    const int c = cnt[row];
    const int* ip = idx + (size_t)row * MAXNZ;
    const int iters = (c + 3) >> 2;

    int j0 = (g < c) ? ip[g] : 0;
    int j1 = (4 + g < c) ? ip[4 + g] : 0;
    bool vok = g < c;
    const float* xjp = xb + (size_t)j0 * DD + s * 4;
    float4 v0 = *(const float4*)(xjp +   0);
    float4 v1 = *(const float4*)(xjp +  64);
    float4 v2 = *(const float4*)(xjp + 128);
    float4 v3 = *(const float4*)(xjp + 192);

    for (int t = 0; t < iters; ++t) {
        int k2 = (t + 2) * 4 + g;
        int j2 = (k2 < c) ? ip[k2] : 0;
        const float* np = xb + (size_t)j1 * DD + s * 4;
        float4 n0 = *(const float4*)(np +   0);
        float4 n1 = *(const float4*)(np +  64);
        float4 n2 = *(const float4*)(np + 128);
        float4 n3 = *(const float4*)(np + 192);

        float q = dot4(y0, v0) + dot4(y1, v1) + dot4(y2, v2) + dot4(y3, v3);
        q += __shfl_xor(q, 1); q += __shfl_xor(q, 2);
        q += __shfl_xor(q, 4); q += __shfl_xor(q, 8);
        float w = vok ? __expf(q) : 0.0f;
        denom += w;
        fma4(a0, w, v0); fma4(a1, w, v1); fma4(a2, w, v2); fma4(a3, w, v3);

        v0 = n0; v1 = n1; v2 = n2; v3 = n3;
        j1 = j2;
        vok = (t + 1) * 4 + g < c;
    }

#define XG(x) x += __shfl_xor(x, 16); x += __shfl_xor(x, 32);
    XG(denom);
    XG(a0.x) XG(a0.y) XG(a0.z) XG(a0.w)
    XG(a1.x) XG(a1.y) XG(a1.z) XG(a1.w)
    XG(a2.x) XG(a2.y) XG(a2.z) XG(a2.w)
    XG(a3.x) XG(a3.y) XG(a3.z) XG(a3.w)
#undef XG

    float inv = 1.0f / denom;
    float4 o = (g == 0) ? a0 : (g == 1) ? a1 : (g == 2) ? a2 : a3;
    o.x *= inv; o.y *= inv; o.z *= inv; o.w *= inv;
    *(float4*)(xout + (size_t)row * DD + g * 64 + s * 4) = o;
}

// ---------------------------------------------------------------------------
// Kernel 3: split-fp16 MFMA GEMM.  C[M,256] = op(A @ W + bias [+ skip])
// A = Ahi + 2^-11 Alo (split on the fly), W pre-split/transposed in wt_hi/lo.
// BM=BN=64, BK=64, 4 waves, wave tile 32x32 (2x2 of 16x16x32 MFMA).
// acc0 = hi*hi, acc1 = hi*lo + lo*hi (recombined with 2^-11 in epilogue).
// LDS tiles XOR-swizzled: byte ^= (row&7)<<4.
// ---------------------------------------------------------------------------
__global__ __launch_bounds__(256, 4) void gemm16(
    const float* __restrict__ A,
    const _Float16* __restrict__ wt_hi, const _Float16* __restrict__ wt_lo,
    const float* __restrict__ bias, const float* __restrict__ skip,
    float* __restrict__ C, int relu)
{
    __shared__ __align__(16) char smem[32768];
    char* Ah = smem;            // [64 m][64 k] fp16, swizzled
    char* Al = smem + 8192;
    char* Bh = smem + 16384;    // [64 n][64 k] fp16, swizzled
    char* Bl = smem + 24576;

    int tid = threadIdx.x;
    int mBase = blockIdx.y * 64;
    int nBase = blockIdx.x * 64;

    // staging coords: thread -> (row sm, k-chunk kc of 16 elements)
    int sm = tid >> 2;
    int kc = (tid & 3) * 16;
    const float*    Ag  = A     + (size_t)(mBase + sm) * 256 + kc;
    const _Float16* Bgh = wt_hi + (size_t)(nBase + sm) * 256 + kc;
    const _Float16* Bgl = wt_lo + (size_t)(nBase + sm) * 256 + kc;
    int sbase = sm * 128 + kc * 2;
    int swz = (sm & 7) << 4;

    int l = tid & 63;
    int wv = tid >> 6;
    int wm = (wv >> 1) * 32, wn = (wv & 1) * 32;
    int lr = l & 15;
    int lkb = (l >> 4) * 16;    // byte offset of lane's 8-halves k-chunk

    f32x4 acc0[2][2] = {};
    f32x4 acc1[2][2] = {};

    for (int kb = 0; kb < 256; kb += 64) {
        float4 f0 = *(const float4*)(Ag + kb + 0);
        float4 f1 = *(const float4*)(Ag + kb + 4);
        float4 f2 = *(const float4*)(Ag + kb + 8);
        float4 f3 = *(const float4*)(Ag + kb + 12);
        int4 gh0 = *(const int4*)(Bgh + kb);
        int4 gh1 = *(const int4*)(Bgh + kb + 8);
        int4 gl0 = *(const int4*)(Bgl + kb);
        int4 gl1 = *(const int4*)(Bgl + kb + 8);

        float xs[16] = {f0.x, f0.y, f0.z, f0.w, f1.x, f1.y, f1.z, f1.w,
                        f2.x, f2.y, f2.z, f2.w, f3.x, f3.y, f3.z, f3.w};
        H8 ah0, ah1, al0, al1;
        #pragma unroll
        for (int i = 0; i < 16; ++i) {
            float x = xs[i];
            _Float16 hi = (_Float16)x;
            float r = x - (float)hi;
            _Float16 lo = (_Float16)(r * 2048.0f);
            if (i < 8) { ah0.h[i] = hi; al0.h[i] = lo; }
            else       { ah1.h[i - 8] = hi; al1.h[i - 8] = lo; }
        }

        __syncthreads();
        *(int4*)(Ah + ((sbase +  0) ^ swz)) = ah0.v;
        *(int4*)(Ah + ((sbase + 16) ^ swz)) = ah1.v;
        *(int4*)(Al + ((sbase +  0) ^ swz)) = al0.v;
        *(int4*)(Al + ((sbase + 16) ^ swz)) = al1.v;
        *(int4*)(Bh + ((sbase +  0) ^ swz)) = gh0;
        *(int4*)(Bh + ((sbase + 16) ^ swz)) = gh1;
        *(int4*)(Bl + ((sbase +  0) ^ swz)) = gl0;
        *(int4*)(Bl + ((sbase + 16) ^ swz)) = gl1;
        __syncthreads();

        #pragma unroll
        for (int kk = 0; kk < 2; ++kk) {
            int kby = kk * 64 + lkb;
            f16x8 fah[2], fal[2], fbh[2], fbl[2];
            #pragma unroll
            for (int mt = 0; mt < 2; ++mt) {
                int ml = wm + mt * 16 + lr;
                int off = (ml * 128 + kby) ^ ((ml & 7) << 4);
                fah[mt] = *(const f16x8*)(Ah + off);
                fal[mt] = *(const f16x8*)(Al + off);
            }
            #pragma unroll
            for (int nt = 0; nt < 2; ++nt) {
                int nl = wn + nt * 16 + lr;
                int off = (nl * 128 + kby) ^ ((nl & 7) << 4);
                fbh[nt] = *(const f16x8*)(Bh + off);
                fbl[nt] = *(const f16x8*)(Bl + off);
            }
            #pragma unroll
            for (int mt = 0; mt < 2; ++mt)
                #pragma unroll
                for (int nt = 0; nt < 2; ++nt) {
                    acc0[mt][nt] = __builtin_amdgcn_mfma_f32_16x16x32_f16(
                        fah[mt], fbh[nt], acc0[mt][nt], 0, 0, 0);
                    acc1[mt][nt] = __builtin_amdgcn_mfma_f32_16x16x32_f16(
                        fah[mt], fbl[nt], acc1[mt][nt], 0, 0, 0);
                    acc1[mt][nt] = __builtin_amdgcn_mfma_f32_16x16x32_f16(
                        fal[mt], fbh[nt], acc1[mt][nt], 0, 0, 0);
                }
        }
    }

    // epilogue: C/D layout col = lane&15, row = (lane>>4)*4 + q
    #pragma unroll
    for (int mt = 0; mt < 2; ++mt) {
        #pragma unroll
        for (int nt = 0; nt < 2; ++nt) {
            int n = nBase + wn + nt * 16 + lr;
            float bval = bias ? bias[n] : 0.0f;
            #pragma unroll
            for (int q = 0; q < 4; ++q) {
                int m = mBase + wm + mt * 16 + (l >> 4) * 4 + q;
                float v = acc0[mt][nt][q] + acc1[mt][nt][q] * 4.8828125e-4f + bval;
                if (relu) v = fmaxf(v, 0.0f);
                if (skip) v += skip[(size_t)m * 256 + n];
                C[(size_t)m * 256 + n] = v;
            }
        }
    }
}

// ---------------------------------------------------------------------------
extern "C" void kernel_launch(void* const* d_in, const int* in_sizes, int n_in,
                              void* d_out, int out_size, void* d_ws, size_t ws_size,
                              hipStream_t stream)
{
    const float* x_in     = (const float*)d_in[0];
    const float* contacts = (const float*)d_in[1];
    const float* W_list   = (const float*)d_in[2];
    const float* dense_W  = (const float*)d_in[3];
    const float* dense_b  = (const float*)d_in[4];
    const float* final_W  = (const float*)d_in[5];
    const float* final_b  = (const float*)d_in[6];
    float* out = (float*)d_out;

    char* ws = (char*)d_ws;
    const size_t bufBytes = (size_t)MROWS * DD * sizeof(float);   // 16.384 MB
    float* bufA = (float*)(ws);
    float* bufB = (float*)(ws + bufBytes);
    float* bufC = (float*)(ws + 2 * bufBytes);
    int*   idx  = (int*)(ws + 3 * bufBytes);
    int*   cnt  = (int*)(ws + 3 * bufBytes + (size_t)MROWS * MAXNZ * sizeof(int));
    float* adiag = (float*)((char*)cnt + (size_t)MROWS * sizeof(int));
    _Float16* wt_hi = (_Float16*)((char*)adiag + (size_t)MROWS * sizeof(float));
    _Float16* wt_lo = wt_hi + (size_t)10 * 65536;
    // total ws use: ~68.5 MB (ws is ~256 MB)

    convert_w<<<160, 256, 0, stream>>>(W_list, dense_W, final_W, wt_hi, wt_lo);
    build_sparse<<<MROWS / 4, 256, 0, stream>>>(contacts, idx, cnt, adiag);

    dim3 gg(DD / 64, MROWS / 64);   // (4, 250)
    const float* curx = x_in;
    for (int l = 0; l < LL; ++l) {
        float* yv = bufA;
        float* ov = (l == 1) ? bufC : bufB;
        // y = x0 @ W_l
        gemm16<<<gg, 256, 0, stream>>>(curx, wt_hi + (size_t)l * 65536,
                                       wt_lo + (size_t)l * 65536,
                                       nullptr, nullptr, yv, 0);
        sparse_agg<<<MROWS / 4, 256, 0, stream>>>(yv, curx, idx, cnt, adiag, ov);
        // dense 1 (relu)
        gemm16<<<gg, 256, 0, stream>>>(ov, wt_hi + (size_t)(3 + l * 2) * 65536,
                                       wt_lo + (size_t)(3 + l * 2) * 65536,
                                       dense_b + (size_t)(l * 2 + 0) * 256,
                                       nullptr, yv, 1);
        // dense 2 (relu) + skip(x0)
        gemm16<<<gg, 256, 0, stream>>>(yv, wt_hi + (size_t)(4 + l * 2) * 65536,
                                       wt_lo + (size_t)(4 + l * 2) * 65536,
                                       dense_b + (size_t)(l * 2 + 1) * 256,
                                       curx, ov, 1);
        curx = ov;
    }
    // final projection
    gemm16<<<gg, 256, 0, stream>>>(curx, wt_hi + (size_t)9 * 65536,
                                   wt_lo + (size_t)9 * 65536,
                                   final_b, nullptr, out, 0);
}

// Round 6
// 295.079 us; speedup vs baseline: 1.7370x; 1.0079x over previous
//
#include <hip/hip_runtime.h>

#define BB 16
#define NN 1000
#define DD 256
#define LL 3
#define MAXNZ 256
#define MROWS (BB * NN)
#define SPLIT_SCALE 2048.0f
#define INV_SPLIT 4.8828125e-4f

typedef _Float16 f16x8 __attribute__((ext_vector_type(8)));
typedef _Float16 f16x2 __attribute__((ext_vector_type(2)));
typedef float f32x4 __attribute__((ext_vector_type(4)));

union H8 { f16x8 v; f16x2 p[4]; _Float16 h[8]; int4 i4; };

#if defined(__has_builtin)
#if __has_builtin(__builtin_amdgcn_fdot2)
#define HAS_FDOT2 1
#endif
#endif

__device__ __forceinline__ float dot2f(f16x2 a, f16x2 b, float c) {
#ifdef HAS_FDOT2
    return __builtin_amdgcn_fdot2(a, b, c, false);
#else
    return fmaf((float)a[0], (float)b[0], fmaf((float)a[1], (float)b[1], c));
#endif
}

// ---------------------------------------------------------------------------
// Kernel 0a: split+transpose the 10 weight matrices -> wt[mat][n][k] hi/lo.
// ---------------------------------------------------------------------------
__global__ __launch_bounds__(256) void convert_w(
    const float* __restrict__ W_list, const float* __restrict__ dense_W,
    const float* __restrict__ final_W,
    _Float16* __restrict__ wt_hi, _Float16* __restrict__ wt_lo)
{
    __shared__ float T[64][68];
    int blk = blockIdx.x;          // 10 mats * 16 tiles
    int mat = blk >> 4;
    int tile = blk & 15;
    int tk = (tile >> 2) * 64, tn = (tile & 3) * 64;
    const float* src = (mat < 3) ? (W_list + (size_t)mat * 65536)
                     : (mat < 9) ? (dense_W + (size_t)(mat - 3) * 65536)
                                 : final_W;
    int t = threadIdx.x;
    {
        int k = t >> 2, nc = (t & 3) * 16;
        const float* sp = src + (size_t)(tk + k) * 256 + tn + nc;
        *(float4*)&T[k][nc + 0]  = *(const float4*)(sp + 0);
        *(float4*)&T[k][nc + 4]  = *(const float4*)(sp + 4);
        *(float4*)&T[k][nc + 8]  = *(const float4*)(sp + 8);
        *(float4*)&T[k][nc + 12] = *(const float4*)(sp + 12);
    }
    __syncthreads();
    int n = t >> 2, kc = (t & 3) * 16;
    H8 hh0, hh1, ll0, ll1;
    #pragma unroll
    for (int i = 0; i < 16; ++i) {
        float x = T[kc + i][n];
        _Float16 hi = (_Float16)x;
        _Float16 lo = (_Float16)((x - (float)hi) * SPLIT_SCALE);
        if (i < 8) { hh0.h[i] = hi; ll0.h[i] = lo; }
        else       { hh1.h[i - 8] = hi; ll1.h[i - 8] = lo; }
    }
    size_t o = (size_t)mat * 65536 + (size_t)(tn + n) * 256 + tk + kc;
    *(int4*)(wt_hi + o)     = hh0.i4;
    *(int4*)(wt_hi + o + 8) = hh1.i4;
    *(int4*)(wt_lo + o)     = ll0.i4;
    *(int4*)(wt_lo + o + 8) = ll1.i4;
}

// ---------------------------------------------------------------------------
// Kernel 0b: split x_in fp32 -> hi/lo fp16 planes.
// ---------------------------------------------------------------------------
__global__ __launch_bounds__(256) void convert_x(
    const float* __restrict__ in, _Float16* __restrict__ hi,
    _Float16* __restrict__ lo)
{
    size_t gid = (size_t)blockIdx.x * 256 + threadIdx.x;
    const float* p = in + gid * 8;
    float4 a = *(const float4*)p;
    float4 b = *(const float4*)(p + 4);
    float xs[8] = {a.x, a.y, a.z, a.w, b.x, b.y, b.z, b.w};
    H8 hh, ll;
    #pragma unroll
    for (int i = 0; i < 8; ++i) {
        _Float16 h = (_Float16)xs[i];
        hh.h[i] = h;
        ll.h[i] = (_Float16)((xs[i] - (float)h) * SPLIT_SCALE);
    }
    *(int4*)(hi + gid * 8) = hh.i4;
    *(int4*)(lo + gid * 8) = ll.i4;
}

// ---------------------------------------------------------------------------
// Kernel 1: build sparse structure of A = prot_contacts + eye.
// ---------------------------------------------------------------------------
__global__ __launch_bounds__(256) void build_sparse(
    const float* __restrict__ contacts,
    int* __restrict__ idx, int* __restrict__ cnt, float* __restrict__ adiag)
{
    int wave = (int)((blockIdx.x * blockDim.x + threadIdx.x) >> 6);
    int lane = threadIdx.x & 63;
    if (wave >= MROWS) return;
    int b = wave / NN;
    int i = wave - b * NN;
    const float* row = contacts + (size_t)b * NN * NN + (size_t)i * NN;
    int* out = idx + (size_t)wave * MAXNZ;
    int count = 0;
    for (int j0 = 0; j0 < NN; j0 += 64) {
        int j = j0 + lane;
        float v = (j < NN) ? row[j] : 0.0f;
        bool p = (v != 0.0f) && (j != i);
        unsigned long long bal = __ballot(p);
        if (p) {
            int pre = __popcll(bal & ((1ull << lane) - 1ull));
            out[count + pre] = j;
        }
        count += __popcll(bal);
    }
    if (lane == 0) {
        cnt[wave] = count;
        adiag[wave] = row[i] + 1.0f;
    }
}

// ---------------------------------------------------------------------------
// Kernel 2: sparse attention aggregate v4 (fp16 gather, dot2, split output).
// 16-lane group s holds dims [8s..8s+7] u [128+8s..128+8s+7].
// Wave = 4 groups = 4 neighbors in flight.
// ---------------------------------------------------------------------------
__global__ __launch_bounds__(256) void sparse_agg(
    const _Float16* __restrict__ yhi,
    const _Float16* __restrict__ xhi, const _Float16* __restrict__ xlo,
    const int* __restrict__ idx, const int* __restrict__ cnt,
    const float* __restrict__ adiag,
    _Float16* __restrict__ ohi, _Float16* __restrict__ olo)
{
    int bid = blockIdx.x;
    int xcd = bid & 7;
    int chunk = bid >> 3;
    int row = xcd * 2000 + chunk * 4 + (int)(threadIdx.x >> 6);
    row = __builtin_amdgcn_readfirstlane(row);
    int lane = threadIdx.x & 63;
    int g = lane >> 4, s = lane & 15;
    int b = row / NN;

    const _Float16* yp = yhi + (size_t)row * DD + s * 8;
    H8 yh0, yh1;
    yh0.i4 = *(const int4*)yp;
    yh1.i4 = *(const int4*)(yp + 128);

    // own row recombined hi+lo (for the diagonal aggregate term)
    const _Float16* xph = xhi + (size_t)row * DD + s * 8;
    const _Float16* xpl = xlo + (size_t)row * DD + s * 8;
    H8 xih0, xih1, xil0, xil1;
    xih0.i4 = *(const int4*)xph;       xih1.i4 = *(const int4*)(xph + 128);
    xil0.i4 = *(const int4*)xpl;       xil1.i4 = *(const int4*)(xpl + 128);
    float xi[16];
    #pragma unroll
    for (int u = 0; u < 8; ++u) {
        xi[u]     = fmaf((float)xil0.h[u], INV_SPLIT, (float)xih0.h[u]);
        xi[8 + u] = fmaf((float)xil1.h[u], INV_SPLIT, (float)xih1.h[u]);
    }
    const _Float16* xb = xhi + (size_t)b * NN * DD;

    // diagonal score
    float p = 0.0f;
    #pragma unroll
    for (int u = 0; u < 8; ++u) {
        p = fmaf((float)yh0.h[u], xi[u], p);
        p = fmaf((float)yh1.h[u], xi[8 + u], p);
    }
    p += __shfl_xor(p, 1); p += __shfl_xor(p, 2);
    p += __shfl_xor(p, 4); p += __shfl_xor(p, 8);
    float wd = (g == 0) ? (__expf(p) + 1e-5f) * adiag[row] : 0.0f;
    float denom = wd;
    float acc[16];
    #pragma unroll
    for (int u = 0; u < 16; ++u) acc[u] = wd * xi[u];

    const int c = cnt[row];
    const int* ip = idx + (size_t)row * MAXNZ;
    const int iters = (c + 3) >> 2;

    int j0 = (g < c) ? ip[g] : 0;
    int j1 = (4 + g < c) ? ip[4 + g] : 0;
    bool vok = g < c;
    H8 v0, v1;
    {
        const _Float16* xp = xb + (size_t)j0 * DD + s * 8;
        v0.i4 = *(const int4*)xp;
        v1.i4 = *(const int4*)(xp + 128);
    }

    for (int t = 0; t < iters; ++t) {
        int k2 = (t + 2) * 4 + g;
        int j2 = (k2 < c) ? ip[k2] : 0;
        H8 n0, n1;
        const _Float16* np = xb + (size_t)j1 * DD + s * 8;
        n0.i4 = *(const int4*)np;
        n1.i4 = *(const int4*)(np + 128);

        float q = 0.0f;
        #pragma unroll
        for (int i = 0; i < 4; ++i) q = dot2f(yh0.p[i], v0.p[i], q);
        #pragma unroll
        for (int i = 0; i < 4; ++i) q = dot2f(yh1.p[i], v1.p[i], q);
        q += __shfl_xor(q, 1); q += __shfl_xor(q, 2);
        q += __shfl_xor(q, 4); q += __shfl_xor(q, 8);
        float w = vok ? __expf(q) : 0.0f;
        denom += w;
        #pragma unroll
        for (int u = 0; u < 8; ++u) {
            acc[u]     = fmaf(w, (float)v0.h[u], acc[u]);
            acc[8 + u] = fmaf(w, (float)v1.h[u], acc[8 + u]);
        }

        v0 = n0; v1 = n1;
        j1 = j2;
        vok = (t + 1) * 4 + g < c;
    }

    // cross-group reduction
#define XG(x) x += __shfl_xor(x, 16); x += __shfl_xor(x, 32);
    XG(denom);
    #pragma unroll
    for (int u = 0; u < 16; ++u) { XG(acc[u]) }
#undef XG

    float inv = 1.0f / denom;
    // group g writes: g0 -> hi chunk0, g1 -> hi chunk1, g2 -> lo c0, g3 -> lo c1
    int half = (g & 1) * 8;
    H8 st;
    #pragma unroll
    for (int i = 0; i < 8; ++i) {
        float x = acc[half + i] * inv;
        _Float16 h = (_Float16)x;
        st.h[i] = (g & 2) ? (_Float16)((x - (float)h) * SPLIT_SCALE) : h;
    }
    _Float16* dst = ((g & 2) ? olo : ohi) + (size_t)row * DD + (g & 1) * 128 + s * 8;
    *(int4*)dst = st.i4;
}

// ---------------------------------------------------------------------------
// Kernel 3: split-fp16 MFMA GEMM v2, pre-split activations in/out.
// BM=64, BN=128, BK=64; 4 waves, wave tile 32x64 (2x4 of 16x16x32 MFMA).
// LDS XOR-swizzle byte ^= (row&7)<<4 on both write and read.
// ---------------------------------------------------------------------------
__global__ __launch_bounds__(256, 3) void gemm16(
    const _Float16* __restrict__ Ahi, const _Float16* __restrict__ Alo,
    const _Float16* __restrict__ Bhi, const _Float16* __restrict__ Blo,
    const float* __restrict__ bias,
    const _Float16* __restrict__ Shi, const _Float16* __restrict__ Slo,
    _Float16* __restrict__ Chi, _Float16* __restrict__ Clo,
    float* __restrict__ Cf32, int relu)
{
    __shared__ __align__(16) char smem[49152];
    char* Ah = smem;             // [64 m][64 k] fp16 swizzled (8 KB)
    char* Al = smem + 8192;
    char* Bh = smem + 16384;     // [128 n][64 k] fp16 swizzled (16 KB)
    char* Bl = smem + 32768;

    int tid = threadIdx.x;
    int mBase = blockIdx.y * 64;
    int nBase = blockIdx.x * 128;

    int sm = tid >> 2, kc = (tid & 3) * 16;     // A staging: row, k-halves
    int sb = tid >> 1, kcb = (tid & 1) * 32;    // B staging
    const _Float16* gAh = Ahi + (size_t)(mBase + sm) * 256 + kc;
    const _Float16* gAl = Alo + (size_t)(mBase + sm) * 256 + kc;
    const _Float16* gBh = Bhi + (size_t)(nBase + sb) * 256 + kcb;
    const _Float16* gBl = Blo + (size_t)(nBase + sb) * 256 + kcb;
    int sbA = sm * 128 + kc * 2, swzA = (sm & 7) << 4;
    int sbB = sb * 128 + kcb * 2, swzB = (sb & 7) << 4;

    int l = tid & 63, wv = tid >> 6;
    int wm = (wv & 1) * 32, wn = (wv >> 1) * 64;
    int lr = l & 15, lkb = (l >> 4) * 16;

    f32x4 acc0[2][4] = {};
    f32x4 acc1[2][4] = {};

    for (int kb = 0; kb < 256; kb += 64) {
        int4 ah0 = *(const int4*)(gAh + kb);
        int4 ah1 = *(const int4*)(gAh + kb + 8);
        int4 al0 = *(const int4*)(gAl + kb);
        int4 al1 = *(const int4*)(gAl + kb + 8);
        int4 bh0 = *(const int4*)(gBh + kb);
        int4 bh1 = *(const int4*)(gBh + kb + 8);
        int4 bh2 = *(const int4*)(gBh + kb + 16);
        int4 bh3 = *(const int4*)(gBh + kb + 24);
        int4 bl0 = *(const int4*)(gBl + kb);
        int4 bl1 = *(const int4*)(gBl + kb + 8);
        int4 bl2 = *(const int4*)(gBl + kb + 16);
        int4 bl3 = *(const int4*)(gBl + kb + 24);

        __syncthreads();
        *(int4*)(Ah + ((sbA +  0) ^ swzA)) = ah0;
        *(int4*)(Ah + ((sbA + 16) ^ swzA)) = ah1;
        *(int4*)(Al + ((sbA +  0) ^ swzA)) = al0;
        *(int4*)(Al + ((sbA + 16) ^ swzA)) = al1;
        *(int4*)(Bh + ((sbB +  0) ^ swzB)) = bh0;
        *(int4*)(Bh + ((sbB + 16) ^ swzB)) = bh1;
        *(int4*)(Bh + ((sbB + 32) ^ swzB)) = bh2;
        *(int4*)(Bh + ((sbB + 48) ^ swzB)) = bh3;
        *(int4*)(Bl + ((sbB +  0) ^ swzB)) = bl0;
        *(int4*)(Bl + ((sbB + 16) ^ swzB)) = bl1;
        *(int4*)(Bl + ((sbB + 32) ^ swzB)) = bl2;
        *(int4*)(Bl + ((sbB + 48) ^ swzB)) = bl3;
        __syncthreads();

        #pragma unroll
        for (int kk = 0; kk < 2; ++kk) {
            int kby = kk * 64 + lkb;
            f16x8 fah[2], fal[2];
            #pragma unroll
            for (int mt = 0; mt < 2; ++mt) {
                int ml = wm + mt * 16 + lr;
                int off = (ml * 128 + kby) ^ ((ml & 7) << 4);
                fah[mt] = *(const f16x8*)(Ah + off);
                fal[mt] = *(const f16x8*)(Al + off);
            }
            f16x8 fbh[4], fbl[4];
            #pragma unroll
            for (int nt = 0; nt < 4; ++nt) {
                int nl = wn + nt * 16 + lr;
                int off = (nl * 128 + kby) ^ ((nl & 7) << 4);
                fbh[nt] = *(const f16x8*)(Bh + off);
                fbl[nt] = *(const f16x8*)(Bl + off);
            }
            #pragma unroll
            for (int mt = 0; mt < 2; ++mt)
                #pragma unroll
                for (int nt = 0; nt < 4; ++nt) {
                    acc0[mt][nt] = __builtin_amdgcn_mfma_f32_16x16x32_f16(
                        fah[mt], fbh[nt], acc0[mt][nt], 0, 0, 0);
                    acc1[mt][nt] = __builtin_amdgcn_mfma_f32_16x16x32_f16(
                        fah[mt], fbl[nt], acc1[mt][nt], 0, 0, 0);
                    acc1[mt][nt] = __builtin_amdgcn_mfma_f32_16x16x32_f16(
                        fal[mt], fbh[nt], acc1[mt][nt], 0, 0, 0);
                }
        }
    }

    #pragma unroll
    for (int mt = 0; mt < 2; ++mt) {
        #pragma unroll
        for (int nt = 0; nt < 4; ++nt) {
            int n = nBase + wn + nt * 16 + lr;
            float bv = bias ? bias[n] : 0.0f;
            #pragma unroll
            for (int q = 0; q < 4; ++q) {
                int m = mBase + wm + mt * 16 + (l >> 4) * 4 + q;
                size_t o = (size_t)m * 256 + n;
                float v = acc0[mt][nt][q] + acc1[mt][nt][q] * INV_SPLIT + bv;
                if (relu) v = fmaxf(v, 0.0f);
                if (Shi) v += (float)Shi[o] + (float)Slo[o] * INV_SPLIT;
                if (Cf32) {
                    Cf32[o] = v;
                } else {
                    _Float16 h = (_Float16)v;
                    Chi[o] = h;
                    Clo[o] = (_Float16)((v - (float)h) * SPLIT_SCALE);
                }
            }
        }
    }
}

// ---------------------------------------------------------------------------
extern "C" void kernel_launch(void* const* d_in, const int* in_sizes, int n_in,
                              void* d_out, int out_size, void* d_ws, size_t ws_size,
                              hipStream_t stream)
{
    const float* x_in     = (const float*)d_in[0];
    const float* contacts = (const float*)d_in[1];
    const float* W_list   = (const float*)d_in[2];
    const float* dense_W  = (const float*)d_in[3];
    const float* dense_b  = (const float*)d_in[4];
    const float* final_W  = (const float*)d_in[5];
    const float* final_b  = (const float*)d_in[6];
    float* out = (float*)d_out;

    char* ws = (char*)d_ws;
    const size_t PL = (size_t)MROWS * DD;          // elements per plane
    _Float16* pl[8];
    for (int i = 0; i < 8; ++i) pl[i] = (_Float16*)ws + (size_t)i * PL;
    char* p8 = ws + 8 * PL * sizeof(_Float16);     // 65.5 MB
    int*   idx   = (int*)p8;
    int*   cnt   = (int*)(p8 + (size_t)MROWS * MAXNZ * sizeof(int));
    float* adiag = (float*)((char*)cnt + (size_t)MROWS * sizeof(int));
    _Float16* wt_hi = (_Float16*)((char*)adiag + (size_t)MROWS * sizeof(float));
    _Float16* wt_lo = wt_hi + (size_t)10 * 65536;
    // total ws use ~85 MB (ws ~256 MB)

    convert_w<<<160, 256, 0, stream>>>(W_list, dense_W, final_W, wt_hi, wt_lo);
    convert_x<<<MROWS * DD / (256 * 8), 256, 0, stream>>>(x_in, pl[0], pl[1]);
    build_sparse<<<MROWS / 4, 256, 0, stream>>>(contacts, idx, cnt, adiag);

    dim3 gg(2, MROWS / 64);   // (2, 250)
    int cur = 0;              // pair index of X0: planes pl[2*cur], pl[2*cur+1]
    for (int l = 0; l < LL; ++l) {
        int oth = 1 - cur;
        _Float16 *x0h = pl[2 * cur], *x0l = pl[2 * cur + 1];
        _Float16 *yh  = pl[2 * oth], *yl  = pl[2 * oth + 1];
        _Float16 *xah = pl[4], *xal = pl[5];
        _Float16 *xbh = pl[6], *xbl = pl[7];
        // y = x0 @ W_l
        gemm16<<<gg, 256, 0, stream>>>(x0h, x0l,
                                       wt_hi + (size_t)l * 65536,
                                       wt_lo + (size_t)l * 65536,
                                       nullptr, nullptr, nullptr,
                                       yh, yl, nullptr, 0);
        // sparse attention aggregate
        sparse_agg<<<MROWS / 4, 256, 0, stream>>>(yh, x0h, x0l, idx, cnt, adiag,
                                                  xah, xal);
        // dense 1 (relu)
        gemm16<<<gg, 256, 0, stream>>>(xah, xal,
                                       wt_hi + (size_t)(3 + l * 2) * 65536,
                                       wt_lo + (size_t)(3 + l * 2) * 65536,
                                       dense_b + (size_t)(l * 2 + 0) * 256,
                                       nullptr, nullptr,
                                       xbh, xbl, nullptr, 1);
        // dense 2 (relu) + skip(x0) -> becomes next X0 (reuses y's pair)
        gemm16<<<gg, 256, 0, stream>>>(xbh, xbl,
                                       wt_hi + (size_t)(4 + l * 2) * 65536,
                                       wt_lo + (size_t)(4 + l * 2) * 65536,
                                       dense_b + (size_t)(l * 2 + 1) * 256,
                                       x0h, x0l,
                                       yh, yl, nullptr, 1);
        cur = oth;
    }
    // final projection -> fp32 d_out
    gemm16<<<gg, 256, 0, stream>>>(pl[2 * cur], pl[2 * cur + 1],
                                   wt_hi + (size_t)9 * 65536,
                                   wt_lo + (size_t)9 * 65536,
                                   final_b, nullptr, nullptr,
                                   nullptr, nullptr, out, 0);
}